// Round 7
// baseline (644.819 us; speedup 1.0000x reference)
//
#include <hip/hip_runtime.h>
#include <hip/hip_bf16.h>
#include <hip/hip_fp16.h>

// Problem constants (match reference)
#define TT 64
#define GN 1024
#define DK 128
#define NN (TT * GN)      // 65536
#define OUTC 131          // 3 + 128
#define TAU 8e-3f         // rescue threshold, 14 sigma of fp16-induced sim error

typedef _Float16 f16x8 __attribute__((ext_vector_type(8)));
typedef float    f32x4 __attribute__((ext_vector_type(4)));

// fp32 -> fp16 round-to-nearest-even, as raw 16 bits
__device__ __forceinline__ unsigned f2h(float f) {
    return (unsigned)__half_as_ushort(__float2half(f));
}

// ---------------------------------------------------------------------------
// Kernel 1: fused fp16 conversion + per-row reciprocal norms (fp64 accum).
// ---------------------------------------------------------------------------
__global__ void kconv(const float* __restrict__ feat, unsigned* __restrict__ fh,
                      float* __restrict__ rnf, double* __restrict__ rnd) {
    int row  = blockIdx.x * 4 + (threadIdx.x >> 6);
    int lane = threadIdx.x & 63;
    const float* fr = feat + (size_t)row * DK;
    float2 v = *(const float2*)(fr + lane * 2);
    fh[(size_t)row * 64 + lane] = f2h(v.x) | (f2h(v.y) << 16);
    double s = (double)v.x * (double)v.x + (double)v.y * (double)v.y;
    #pragma unroll
    for (int off = 32; off > 0; off >>= 1)
        s += __shfl_down(s, off);
    if (lane == 0) {
        double m = sqrt(s);
        if (m < 1e-6) m = 1e-6;
        double r = 1.0 / m;
        rnd[row] = r;
        rnf[row] = (float)r;
    }
}

// ---------------------------------------------------------------------------
// Kernel 2: best-cosine-match graph, register fp16 MFMA. Block = (t, gt) with
// 64 A-rows; wave w owns ALL 64 rows x B-rows [w*256, w*256+256) (16 chunks).
// A fragments live in registers (loaded once); B streamed with one-chunk
// register prefetch; 16 MFMAs per 4KB of loads (4 independent acc chains).
// B is read once per block -> 4 MB L2 traffic per t (L2-resident).
// Butterfly + tiny LDS merge; fp64 rescue for gap < TAU (exact R1-R6 path).
// ---------------------------------------------------------------------------
__global__ __launch_bounds__(256) void ksim(const float* __restrict__ feat,
                                            const unsigned* __restrict__ fh,
                                            const float* __restrict__ rnf,
                                            const double* __restrict__ rnd,
                                            int* __restrict__ nxt) {
    __shared__ float mg1[64 * 4], mg2[64 * 4];
    __shared__ int   mgi[64 * 4];
    __shared__ int nflag;
    __shared__ int lst[64];

    int id = blockIdx.x;
    int t  = (id & 7) + 8 * ((id >> 3) & 7);   // same t -> same XCD (id%8)
    int gt = id >> 6;                          // 0..15
    if (t >= TT - 1) return;                   // 16 idle blocks (t==63)
    if (threadIdx.x == 0) nflag = 0;

    int tid  = threadIdx.x;
    int wave = tid >> 6;
    int lane = tid & 63;
    int la = lane & 15;                        // fragment row/col within 16-tile
    int lq = lane >> 4;                        // quad (k slice)

    // row-major fp16 rows = 64 ints each
    const int* Ah = (const int*)fh + (size_t)(t * GN + gt * 64) * 64;
    const int* Bh = (const int*)fh + (size_t)(t + 1) * GN * 64;
    const float* rB = rnf + (size_t)(t + 1) * GN + wave * 256;

    // A fragments: af[at][kc] covers A row at*16+la, halves kc*32 + lq*8 ..
    f16x8 af[4][4];
    #pragma unroll
    for (int at = 0; at < 4; ++at) {
        const int* Ar = Ah + (at * 16 + la) * 64 + lq * 4;
        #pragma unroll
        for (int kc = 0; kc < 4; ++kc)
            af[at][kc] = __builtin_bit_cast(f16x8, *(const int4*)(Ar + kc * 16));
    }

    // per-lane top-2 over 16 m-slots; slot s=at*4+reg -> row at*16+lq*4+reg
    float t1[16], t2[16]; int i1[16];
    #pragma unroll
    for (int s = 0; s < 16; ++s) { t1[s] = -3.4e38f; t2[s] = -3.4e38f; i1[s] = 0x7fffffff; }

    const int* Bl = Bh + ((size_t)wave * 256 + la) * 64 + lq * 4;

    int4 bcur[4];
    #pragma unroll
    for (int kc = 0; kc < 4; ++kc) bcur[kc] = *(const int4*)(Bl + kc * 16);
    float rncur = rB[la];

    #pragma unroll 4
    for (int c = 0; c < 16; ++c) {
        int4 bnxt[4]; float rnnxt = 0.f;
        if (c < 15) {
            const int* Bn = Bl + (c + 1) * 16 * 64;
            #pragma unroll
            for (int kc = 0; kc < 4; ++kc) bnxt[kc] = *(const int4*)(Bn + kc * 16);
            rnnxt = rB[(c + 1) * 16 + la];
        }

        f32x4 acc[4];
        #pragma unroll
        for (int at = 0; at < 4; ++at) acc[at] = (f32x4){0.f, 0.f, 0.f, 0.f};
        #pragma unroll
        for (int at = 0; at < 4; ++at)
            #pragma unroll
            for (int kc = 0; kc < 4; ++kc)
                acc[at] = __builtin_amdgcn_mfma_f32_16x16x32_f16(
                    af[at][kc], __builtin_bit_cast(f16x8, bcur[kc]), acc[at], 0, 0, 0);

        int n = wave * 256 + c * 16 + la;      // ascending per lane -> first-max
        #pragma unroll
        for (int at = 0; at < 4; ++at) {
            #pragma unroll
            for (int reg = 0; reg < 4; ++reg) {
                float v = acc[at][reg] * rncur;
                int s = at * 4 + reg;
                t2[s] = fmaxf(t2[s], fminf(v, t1[s]));   // med3(v, t1, t2)
                if (v > t1[s]) { t1[s] = v; i1[s] = n; }
            }
        }

        if (c < 15) {
            #pragma unroll
            for (int kc = 0; kc < 4; ++kc) bcur[kc] = bnxt[kc];
            rncur = rnnxt;
        }
    }

    // ---- butterfly top-2 merge across the 16 la-lanes (same lq group) ----
    #pragma unroll
    for (int m = 1; m <= 8; m <<= 1) {
        #pragma unroll
        for (int s = 0; s < 16; ++s) {
            float o1 = __shfl_xor(t1[s], m);
            float o2 = __shfl_xor(t2[s], m);
            int   oi = __shfl_xor(i1[s], m);
            bool take = (o1 > t1[s]) || (o1 == t1[s] && oi < i1[s]);
            float nt2 = take ? fmaxf(o2, t1[s]) : fmaxf(t2[s], o1);
            if (take) { t1[s] = o1; i1[s] = oi; }
            t2[s] = nt2;
        }
    }

    // ---- cross-wave merge via tiny LDS arrays [64 rows][4 waves] ----
    if (la == 0) {
        #pragma unroll
        for (int s = 0; s < 16; ++s) {
            int m = (s >> 2) * 16 + lq * 4 + (s & 3);   // row within block
            mg1[m * 4 + wave] = t1[s];
            mg2[m * 4 + wave] = t2[s];
            mgi[m * 4 + wave] = i1[s];
        }
    }
    __syncthreads();

    if (tid < 64) {
        float best = -3.4e38f, sec = -3.4e38f, bw2 = -3.4e38f;
        int bi = 0x7fffffff;
        #pragma unroll
        for (int w = 0; w < 4; ++w) {          // w ascending = n ascending
            float v1 = mg1[tid * 4 + w];
            float v2 = mg2[tid * 4 + w];
            int  idx = mgi[tid * 4 + w];
            if (v1 > best || (v1 == best && idx < bi)) {
                sec = fmaxf(sec, best);
                best = v1; bi = idx; bw2 = v2;
            } else {
                sec = fmaxf(sec, v1);
            }
        }
        sec = fmaxf(sec, bw2);
        if (best - sec < TAU) {
            int p = atomicAdd(&nflag, 1);
            lst[p] = tid;                      // fp64 rescue
        } else {
            nxt[t * GN + gt * 64 + tid] = (t + 1) * GN + bi;
        }
    }
    __syncthreads();

    // ---- fp64 rescue, wave-parallel (exact: matches rounds 1-6 fp64 path) ----
    int nf = nflag;
    const float* Bf = feat + (size_t)(t + 1) * GN * DK;
    for (int fi = wave; fi < nf; fi += 4) {
        int r = lst[fi];
        const float* Arow = feat + (size_t)(t * GN + gt * 64 + r) * DK;
        double bv = -1e300; int bi2 = 0x7fffffff;
        for (int hh = 0; hh < 16; ++hh) {
            int h = hh * 64 + lane;
            const float* Brow = Bf + (size_t)h * DK;
            double s = 0.0;
            #pragma unroll 8
            for (int k = 0; k < DK; k += 4) {
                float4 a = *(const float4*)(Arow + k);
                float4 b = *(const float4*)(Brow + k);
                s = fma((double)a.x, (double)b.x, s);
                s = fma((double)a.y, (double)b.y, s);
                s = fma((double)a.z, (double)b.z, s);
                s = fma((double)a.w, (double)b.w, s);
            }
            s *= rnd[(t + 1) * GN + h];
            if (s > bv || (s == bv && h < bi2)) { bv = s; bi2 = h; }
        }
        #pragma unroll
        for (int off = 32; off > 0; off >>= 1) {
            double ov = __shfl_down(bv, off);
            int    oi = __shfl_down(bi2, off);
            if (ov > bv || (ov == bv && oi < bi2)) { bv = ov; bi2 = oi; }
        }
        if (lane == 0) nxt[t * GN + gt * 64 + r] = (t + 1) * GN + bi2;
    }
}

// ---------------------------------------------------------------------------
// Kernel 3: chain propagation + lengths + kept-offset scan, one block.
// Packed winner word = (chain_priority << 7) | length; double-buffered.
// ---------------------------------------------------------------------------
__global__ void kgraph(const int* __restrict__ nxt, int* __restrict__ chain_of,
                       int* __restrict__ clen, const int* __restrict__ minp,
                       int* __restrict__ offset) {
    __shared__ int winner[2 * GN];
    __shared__ int psum[1024];
    int g = threadIdx.x;            // 0..1023
    int mychain = g, mylen = 1;     // group 0: every node starts a chain
    chain_of[g] = g;
    winner[g] = 0x7fffffff;         // buffer 0 init
    int nxt_cur = nxt[g];           // prefetch t=0
    __syncthreads();
    for (int t = 0; t < TT - 1; ++t) {
        int* Wa = winner + (t & 1) * GN;
        int* Wb = winner + ((t + 1) & 1) * GN;
        int j = nxt_cur - (t + 1) * GN;         // target slot in next group
        if (t + 1 < TT - 1) nxt_cur = nxt[(t + 1) * GN + g];   // prefetch
        atomicMin(&Wa[j], (mychain << 7) | mylen);
        Wb[g] = 0x7fffffff;                     // prep next buffer
        __syncthreads();
        int w  = Wa[g];
        int wj = Wa[j];
        if ((wj >> 7) != mychain) clen[mychain] = mylen;   // chain dies here
        int node = (t + 1) * GN + g;
        if (w == 0x7fffffff) { mychain = node; mylen = 1; }
        else                 { mychain = w >> 7; mylen = (w & 127) + 1; }
        chain_of[node] = mychain;
        __syncthreads();            // Wa reads done before t+2 resets it
    }
    clen[mychain] = mylen;          // surviving chains end at group 63
    __syncthreads();

    // exclusive prefix sum of kept chain lengths over start indices
    int ml = *minp;
    int base = g * 64;
    int local = 0;
    for (int e = 0; e < 64; ++e) {
        int s = base + e;
        if (chain_of[s] == s) { int cl = clen[s]; if (cl >= ml) local += cl; }
    }
    psum[g] = local;
    __syncthreads();
    for (int off = 1; off < 1024; off <<= 1) {
        int add = (g >= off) ? psum[g - off] : 0;
        __syncthreads();
        psum[g] += add;
        __syncthreads();
    }
    int run = g ? psum[g - 1] : 0;
    for (int e = 0; e < 64; ++e) {
        int s = base + e;
        int v = 0;
        if (chain_of[s] == s) { int cl = clen[s]; if (cl >= ml) v = cl; }
        offset[s] = run;
        run += v;
    }
}

// ---------------------------------------------------------------------------
// Kernel 4: scatter kept rows, one wave per node (4 nodes / 256-thr block).
// ---------------------------------------------------------------------------
__global__ void kscatter(const float* __restrict__ coor, const float* __restrict__ feat,
                         const int* __restrict__ chain_of, const int* __restrict__ clen,
                         const int* __restrict__ offset, const int* __restrict__ minp,
                         float* __restrict__ out) {
    int node = blockIdx.x * 4 + (threadIdx.x >> 6);
    int lane = threadIdx.x & 63;
    int s = chain_of[node];
    if (clen[s] < *minp) return;
    int row = offset[s] + (node >> 10) - (s >> 10);
    float* orow = out + (size_t)row * OUTC;
    const float* f = feat + (size_t)node * DK;
    if (lane < 3) orow[lane] = coor[(size_t)node * 3 + lane];
    orow[3 + lane]  = f[lane];
    orow[67 + lane] = f[64 + lane];
}

// ---------------------------------------------------------------------------
extern "C" void kernel_launch(void* const* d_in, const int* in_sizes, int n_in,
                              void* d_out, int out_size, void* d_ws, size_t ws_size,
                              hipStream_t stream) {
    const float* coor   = (const float*)d_in[0];   // [N,3]
    const float* feat   = (const float*)d_in[1];   // [N,128]
    const int*   minlen = (const int*)d_in[2];     // scalar
    float*       out    = (float*)d_out;           // [N,131] fp32

    char* ws = (char*)d_ws;
    double*   rnd      = (double*)(ws);                            // N doubles
    float*    rnf      = (float*)(ws + (size_t)NN * 8);            // N floats
    int*      nxt      = (int*)(ws + (size_t)NN * 12);
    int*      chain_of = (int*)(ws + (size_t)NN * 16);
    int*      clen     = (int*)(ws + (size_t)NN * 20);
    int*      offset   = (int*)(ws + (size_t)NN * 24);
    unsigned* fh       = (unsigned*)(ws + (size_t)NN * 28);        // N*128 fp16 = 16 MB

    hipMemsetAsync(d_out, 0, (size_t)out_size * sizeof(float), stream);

    kconv<<<NN / 4, 256, 0, stream>>>(feat, fh, rnf, rnd);

    ksim<<<1024, 256, 0, stream>>>(feat, fh, rnf, rnd, nxt);

    kgraph<<<1, GN, 0, stream>>>(nxt, chain_of, clen, minlen, offset);
    kscatter<<<NN / 4, 256, 0, stream>>>(coor, feat, chain_of, clen, offset, minlen, out);
}

// Round 8
// 512.705 us; speedup vs baseline: 1.2577x; 1.2577x over previous
//
#include <hip/hip_runtime.h>
#include <hip/hip_bf16.h>
#include <hip/hip_fp16.h>

// Problem constants (match reference)
#define TT 64
#define GN 1024
#define DK 128
#define NN (TT * GN)      // 65536
#define OUTC 131          // 3 + 128
#define TAU 8e-3f         // rescue threshold, 14 sigma of fp16-induced sim error

typedef _Float16 f16x8 __attribute__((ext_vector_type(8)));
typedef float    f32x4 __attribute__((ext_vector_type(4)));

// fp32 -> fp16 round-to-nearest-even, as raw 16 bits
__device__ __forceinline__ unsigned f2h(float f) {
    return (unsigned)__half_as_ushort(__float2half(f));
}

// async global->LDS, 16 B per lane; LDS dest must be lane-contiguous (m104)
__device__ __forceinline__ void gload_lds16(const void* g, void* l) {
    __builtin_amdgcn_global_load_lds(
        (const __attribute__((address_space(1))) unsigned int*)g,
        (__attribute__((address_space(3))) unsigned int*)l, 16, 0, 0);
}

// ---------------------------------------------------------------------------
// Kernel 1: fused fp16 conversion + per-row reciprocal norms (fp64 accum).
// ---------------------------------------------------------------------------
__global__ void kconv(const float* __restrict__ feat, unsigned* __restrict__ fh,
                      float* __restrict__ rnf, double* __restrict__ rnd) {
    int row  = blockIdx.x * 4 + (threadIdx.x >> 6);
    int lane = threadIdx.x & 63;
    const float* fr = feat + (size_t)row * DK;
    float2 v = *(const float2*)(fr + lane * 2);
    fh[(size_t)row * 64 + lane] = f2h(v.x) | (f2h(v.y) << 16);
    double s = (double)v.x * (double)v.x + (double)v.y * (double)v.y;
    #pragma unroll
    for (int off = 32; off > 0; off >>= 1)
        s += __shfl_down(s, off);
    if (lane == 0) {
        double m = sqrt(s);
        if (m < 1e-6) m = 1e-6;
        double r = 1.0 / m;
        rnd[row] = r;
        rnf[row] = (float)r;
    }
}

// ---------------------------------------------------------------------------
// Kernel 2: 4032 independent 128x128x128 GEMM tile blocks (t, mt, nt).
// Stage A+B tiles (fp16, 32 KB each) via global_load_lds w/ source-side XOR
// granule swizzle (granule=16B; LDS (row,colL) holds global (row, colL^(row&7))
// -> frag ds_read_b128 is 2-way bank-free). 4 waves, wave tile 64x64,
// 16x16x32 MFMA. Output: per-row top-2 over this block's 128 cols -> tws.
// ---------------------------------------------------------------------------
__global__ __launch_bounds__(256) void ksim(const unsigned* __restrict__ fh,
                                            const float* __restrict__ rnf,
                                            float4* __restrict__ tws) {
    __shared__ int Atile[8192];    // 128 rows x 16 granules (32 KB)
    __shared__ int Btile[8192];

    int id = blockIdx.x;           // t*64 + mt*8 + nt ; id%8 = nt -> same-nt same-XCD
    int t  = id >> 6;              // 0..62
    int mt = (id >> 3) & 7;
    int nt = id & 7;

    int tid  = threadIdx.x;
    int wave = tid >> 6;
    int lane = tid & 63;
    int la = lane & 15;
    int lq = lane >> 4;
    int wr = (wave & 1) * 64;      // wave row offset
    int wc = (wave >> 1) * 64;     // wave col offset

    const int* Ag = (const int*)fh + ((size_t)t * GN + mt * 128) * 64;
    const int* Bg = (const int*)fh + ((size_t)(t + 1) * GN + nt * 128) * 64;

    // stage both tiles: 8 issues each, lane-contiguous LDS, swizzled source
    #pragma unroll
    for (int i = 0; i < 8; ++i) {
        int L = i * 256 + tid;         // granule index in tile
        int row = L >> 4, colL = L & 15;
        int colG = colL ^ (row & 7);
        gload_lds16(Ag + row * 64 + colG * 4, &Atile[L * 4]);
        gload_lds16(Bg + row * 64 + colG * 4, &Btile[L * 4]);
    }
    __syncthreads();                   // includes vmcnt(0) drain

    f32x4 acc[4][4];
    #pragma unroll
    for (int at = 0; at < 4; ++at)
        #pragma unroll
        for (int ct = 0; ct < 4; ++ct) acc[at][ct] = (f32x4){0.f, 0.f, 0.f, 0.f};

    #pragma unroll
    for (int kc = 0; kc < 4; ++kc) {
        int sw = ((kc * 4 + lq) ^ (la & 7)) << 2;   // swizzled in-row int offset
        f16x8 af[4], bf[4];
        #pragma unroll
        for (int x = 0; x < 4; ++x) {
            af[x] = __builtin_bit_cast(f16x8, *(const int4*)&Atile[(wr + x * 16 + la) * 64 + sw]);
            bf[x] = __builtin_bit_cast(f16x8, *(const int4*)&Btile[(wc + x * 16 + la) * 64 + sw]);
        }
        #pragma unroll
        for (int at = 0; at < 4; ++at)
            #pragma unroll
            for (int ct = 0; ct < 4; ++ct)
                acc[at][ct] = __builtin_amdgcn_mfma_f32_16x16x32_f16(
                    af[at], bf[ct], acc[at][ct], 0, 0, 0);
    }

    // ---- per-lane top-2 over this block's cols (C layout: col=la, row=lq*4+reg)
    float t1[16], t2[16]; int i1[16];
    #pragma unroll
    for (int s = 0; s < 16; ++s) { t1[s] = -3.4e38f; t2[s] = -3.4e38f; i1[s] = 0x7fffffff; }

    const float* rB = rnf + (size_t)(t + 1) * GN + nt * 128;
    #pragma unroll
    for (int ct = 0; ct < 4; ++ct) {               // ct ascending = n ascending
        int cloc = wc + ct * 16 + la;
        int n = nt * 128 + cloc;
        float rn = rB[cloc];
        #pragma unroll
        for (int at = 0; at < 4; ++at) {
            #pragma unroll
            for (int reg = 0; reg < 4; ++reg) {
                float v = acc[at][ct][reg] * rn;
                int s = at * 4 + reg;
                t2[s] = fmaxf(t2[s], fminf(v, t1[s]));   // med3(v,t1,t2)
                if (v > t1[s]) { t1[s] = v; i1[s] = n; }
            }
        }
    }

    // butterfly top-2 merge over the 16 la-lanes (same lq group)
    #pragma unroll
    for (int m = 1; m <= 8; m <<= 1) {
        #pragma unroll
        for (int s = 0; s < 16; ++s) {
            float o1 = __shfl_xor(t1[s], m);
            float o2 = __shfl_xor(t2[s], m);
            int   oi = __shfl_xor(i1[s], m);
            bool take = (o1 > t1[s]) || (o1 == t1[s] && oi < i1[s]);
            float nt2 = take ? fmaxf(o2, t1[s]) : fmaxf(t2[s], o1);
            if (take) { t1[s] = o1; i1[s] = oi; }
            t2[s] = nt2;
        }
    }

    // cross-wave merge (2 column halves) via overlay on Atile
    __syncthreads();                   // all tile reads done
    float* mv1 = (float*)Atile;        // [128][2]
    float* mv2 = mv1 + 256;
    int*   mi1 = (int*)(mv2 + 256);
    if (la == 0) {
        #pragma unroll
        for (int s = 0; s < 16; ++s) {
            int row = wr + (s >> 2) * 16 + lq * 4 + (s & 3);
            int idx = row * 2 + (wave >> 1);
            mv1[idx] = t1[s]; mv2[idx] = t2[s]; mi1[idx] = i1[s];
        }
    }
    __syncthreads();

    if (tid < 128) {
        float best = mv1[tid * 2], sec, bw2 = mv2[tid * 2];
        int bi = mi1[tid * 2];
        float v1 = mv1[tid * 2 + 1], v2 = mv2[tid * 2 + 1];
        int  ii = mi1[tid * 2 + 1];
        if (v1 > best || (v1 == best && ii < bi)) {
            sec = fmaxf(best, v2); best = v1; bi = ii;   // winner half 1
        } else {
            sec = fmaxf(v1, bw2);
        }
        float4 o; o.x = best; o.y = sec; o.z = __int_as_float(bi); o.w = 0.f;
        tws[((size_t)t * GN + mt * 128 + tid) * 8 + nt] = o;
    }
}

// ---------------------------------------------------------------------------
// Kernel 3: merge 8 colblock candidates per row; gap<TAU -> rescue list.
// ---------------------------------------------------------------------------
__global__ void kmerge(const float4* __restrict__ tws, int* __restrict__ nxt,
                       int* __restrict__ rcount, int* __restrict__ rlist) {
    int idx = blockIdx.x * 256 + threadIdx.x;      // 0..64511
    int t = idx >> 10, grow = idx & 1023;
    const float4* e = tws + (size_t)idx * 8;
    float best = -3.4e38f, sec = -3.4e38f, bw2 = -3.4e38f;
    int bi = 0x7fffffff;
    #pragma unroll
    for (int nb = 0; nb < 8; ++nb) {               // nb ascending = n ascending
        float4 v = e[nb];
        int ii = __float_as_int(v.z);
        if (v.x > best || (v.x == best && ii < bi)) {
            sec = fmaxf(sec, best);
            best = v.x; bi = ii; bw2 = v.y;
        } else {
            sec = fmaxf(sec, v.x);
        }
    }
    sec = fmaxf(sec, bw2);
    if (best - sec < TAU) {
        int p = atomicAdd(rcount, 1);
        rlist[p] = idx;
    } else {
        nxt[t * GN + grow] = (t + 1) * GN + bi;
    }
}

// ---------------------------------------------------------------------------
// Kernel 4: fp64 rescue (exact: same math/tie rules as rounds 1-7).
// Grid-strided over the dynamic rescue count.
// ---------------------------------------------------------------------------
__global__ void krescue(const float* __restrict__ feat, const double* __restrict__ rnd,
                        const int* __restrict__ rcount, const int* __restrict__ rlist,
                        int* __restrict__ nxt) {
    __shared__ double sv[4];
    __shared__ int    si[4];
    int nr = *rcount;
    int tid = threadIdx.x, lane = tid & 63, wave = tid >> 6;
    for (int fi = blockIdx.x; fi < nr; fi += gridDim.x) {
        int idx = rlist[fi];
        int t = idx >> 10, grow = idx & 1023;
        const float* Arow = feat + ((size_t)t * GN + grow) * DK;
        const float* Bf   = feat + (size_t)(t + 1) * GN * DK;
        double bv = -1e300; int bi = 0x7fffffff;
        #pragma unroll
        for (int j = 0; j < 4; ++j) {
            int h = j * 256 + tid;
            const float* Brow = Bf + (size_t)h * DK;
            double s = 0.0;
            #pragma unroll 8
            for (int k = 0; k < DK; k += 4) {
                float4 a = *(const float4*)(Arow + k);
                float4 b = *(const float4*)(Brow + k);
                s = fma((double)a.x, (double)b.x, s);
                s = fma((double)a.y, (double)b.y, s);
                s = fma((double)a.z, (double)b.z, s);
                s = fma((double)a.w, (double)b.w, s);
            }
            s *= rnd[(t + 1) * GN + h];
            if (s > bv || (s == bv && h < bi)) { bv = s; bi = h; }
        }
        #pragma unroll
        for (int off = 32; off > 0; off >>= 1) {
            double ov = __shfl_down(bv, off);
            int    oi = __shfl_down(bi, off);
            if (ov > bv || (ov == bv && oi < bi)) { bv = ov; bi = oi; }
        }
        if (lane == 0) { sv[wave] = bv; si[wave] = bi; }
        __syncthreads();
        if (tid == 0) {
            double b2 = sv[0]; int i2 = si[0];
            #pragma unroll
            for (int w = 1; w < 4; ++w)
                if (sv[w] > b2 || (sv[w] == b2 && si[w] < i2)) { b2 = sv[w]; i2 = si[w]; }
            nxt[t * GN + grow] = (t + 1) * GN + i2;
        }
        __syncthreads();
    }
}

// ---------------------------------------------------------------------------
// Kernel 5: chain propagation + lengths + kept-offset scan + total, one block.
// ---------------------------------------------------------------------------
__global__ void kgraph(const int* __restrict__ nxt, int* __restrict__ chain_of,
                       int* __restrict__ clen, const int* __restrict__ minp,
                       int* __restrict__ offset, int* __restrict__ total) {
    __shared__ int winner[2 * GN];
    __shared__ int psum[1024];
    int g = threadIdx.x;            // 0..1023
    int mychain = g, mylen = 1;     // group 0: every node starts a chain
    chain_of[g] = g;
    winner[g] = 0x7fffffff;         // buffer 0 init
    int nxt_cur = nxt[g];           // prefetch t=0
    __syncthreads();
    for (int t = 0; t < TT - 1; ++t) {
        int* Wa = winner + (t & 1) * GN;
        int* Wb = winner + ((t + 1) & 1) * GN;
        int j = nxt_cur - (t + 1) * GN;         // target slot in next group
        if (t + 1 < TT - 1) nxt_cur = nxt[(t + 1) * GN + g];   // prefetch
        atomicMin(&Wa[j], (mychain << 7) | mylen);
        Wb[g] = 0x7fffffff;                     // prep next buffer
        __syncthreads();
        int w  = Wa[g];
        int wj = Wa[j];
        if ((wj >> 7) != mychain) clen[mychain] = mylen;   // chain dies here
        int node = (t + 1) * GN + g;
        if (w == 0x7fffffff) { mychain = node; mylen = 1; }
        else                 { mychain = w >> 7; mylen = (w & 127) + 1; }
        chain_of[node] = mychain;
        __syncthreads();            // Wa reads done before t+2 resets it
    }
    clen[mychain] = mylen;          // surviving chains end at group 63
    __syncthreads();

    // exclusive prefix sum of kept chain lengths over start indices
    int ml = *minp;
    int base = g * 64;
    int local = 0;
    for (int e = 0; e < 64; ++e) {
        int s = base + e;
        if (chain_of[s] == s) { int cl = clen[s]; if (cl >= ml) local += cl; }
    }
    psum[g] = local;
    __syncthreads();
    for (int off = 1; off < 1024; off <<= 1) {
        int add = (g >= off) ? psum[g - off] : 0;
        __syncthreads();
        psum[g] += add;
        __syncthreads();
    }
    int run = g ? psum[g - 1] : 0;
    for (int e = 0; e < 64; ++e) {
        int s = base + e;
        int v = 0;
        if (chain_of[s] == s) { int cl = clen[s]; if (cl >= ml) v = cl; }
        offset[s] = run;
        run += v;
    }
    if (g == 1023) *total = run;    // total kept rows
}

// ---------------------------------------------------------------------------
// Kernel 6: zero only the non-kept tail of the output.
// ---------------------------------------------------------------------------
__global__ void kzero(const int* __restrict__ total, float* __restrict__ out) {
    long start = (long)(*total) * OUTC;
    long end   = (long)NN * OUTC;
    long gid   = (long)blockIdx.x * 256 + threadIdx.x;
    long stride = (long)gridDim.x * 256;
    for (long i = start + gid; i < end; i += stride) out[i] = 0.f;
}

// ---------------------------------------------------------------------------
// Kernel 7: scatter kept rows, one wave per node (4 nodes / 256-thr block).
// ---------------------------------------------------------------------------
__global__ void kscatter(const float* __restrict__ coor, const float* __restrict__ feat,
                         const int* __restrict__ chain_of, const int* __restrict__ clen,
                         const int* __restrict__ offset, const int* __restrict__ minp,
                         float* __restrict__ out) {
    int node = blockIdx.x * 4 + (threadIdx.x >> 6);
    int lane = threadIdx.x & 63;
    int s = chain_of[node];
    if (clen[s] < *minp) return;
    int row = offset[s] + (node >> 10) - (s >> 10);
    float* orow = out + (size_t)row * OUTC;
    const float* f = feat + (size_t)node * DK;
    if (lane < 3) orow[lane] = coor[(size_t)node * 3 + lane];
    orow[3 + lane]  = f[lane];
    orow[67 + lane] = f[64 + lane];
}

// ---------------------------------------------------------------------------
extern "C" void kernel_launch(void* const* d_in, const int* in_sizes, int n_in,
                              void* d_out, int out_size, void* d_ws, size_t ws_size,
                              hipStream_t stream) {
    const float* coor   = (const float*)d_in[0];   // [N,3]
    const float* feat   = (const float*)d_in[1];   // [N,128]
    const int*   minlen = (const int*)d_in[2];     // scalar
    float*       out    = (float*)d_out;           // [N,131] fp32

    char* ws = (char*)d_ws;
    double*   rnd      = (double*)(ws);                    // 512 KB
    float*    rnf      = (float*)(ws + 524288);            // 256 KB
    int*      nxt      = (int*)(ws + 786432);              // 256 KB
    int*      chain_of = (int*)(ws + 1048576);             // 256 KB
    int*      clen     = (int*)(ws + 1310720);             // 256 KB
    int*      offset   = (int*)(ws + 1572864);             // 256 KB
    int*      total    = (int*)(ws + 1835008);
    int*      rcount   = (int*)(ws + 1835264);
    int*      rlist    = (int*)(ws + 1835520);             // 256 KB (worst case)
    unsigned* fh       = (unsigned*)(ws + 2097152);        // 16 MB
    float4*   tws      = (float4*)(ws + 18874368);         // 8.25 MB

    hipMemsetAsync(rcount, 0, 4, stream);

    kconv<<<NN / 4, 256, 0, stream>>>(feat, fh, rnf, rnd);

    ksim<<<63 * 64, 256, 0, stream>>>(fh, rnf, tws);

    kmerge<<<63 * GN / 256, 256, 0, stream>>>(tws, nxt, rcount, rlist);
    krescue<<<512, 256, 0, stream>>>(feat, rnd, rcount, rlist, nxt);

    kgraph<<<1, GN, 0, stream>>>(nxt, chain_of, clen, minlen, offset, total);
    kzero<<<2048, 256, 0, stream>>>(total, out);
    kscatter<<<NN / 4, 256, 0, stream>>>(coor, feat, chain_of, clen, offset, minlen, out);
}